// Round 9
// baseline (259.372 us; speedup 1.0000x reference)
//
#include <hip/hip_runtime.h>

#define NB 16
#define NEV 960000
#define NS 48
#define SEG 20000
#define S_IDX 3
#define E_IDX 38
#define N_ITER 34
#define ND 256
#define NCH 35          // chunks S_IDX .. E_IDX-1

// ---------------- centroid: preload-then-reduce ----------------------------
// Bit-identical math to the original stats_kernel: same tap order, same
// double accumulation, same 64-lane shfl_down reduction. The 20 taps are
// preloaded into registers (independent, fully unrolled -> static indexing)
// so global latency is paid ONCE per centroid, not 20x serially.
__device__ inline void centroid_pl(const float* __restrict__ along,  // [NS*ND]
                                   float cv, int sI, int lane,
                                   float* mf_out, int* ai_out) {
    float vals[4][5];
    #pragma unroll
    for (int k = 0; k < 4; ++k) {
        int d = lane + 64 * k;
        #pragma unroll
        for (int ds = -2; ds <= 2; ++ds) {
            int ss = sI + ds;
            vals[k][ds + 2] = (ss >= 0 && ss < NS) ? along[ss * ND + d] : 0.0f;
        }
    }
    double acc = 0.0;
    #pragma unroll
    for (int k = 0; k < 4; ++k) {
        int d = lane + 64 * k;
        int lo = d - 2 < 0 ? 0 : d - 2;
        int hi = d + 2 > 255 ? 255 : d + 2;
        double Wd = 0.5 * (double)(lo + hi) * (double)(hi - lo + 1);
        double t = 0.0;
        #pragma unroll
        for (int ds = -2; ds <= 2; ++ds) {
            int ss = sI + ds;
            if (ss >= 0 && ss < NS) t += (double)fminf(vals[k][ds + 2], cv);
        }
        acc += t * Wd;
    }
    for (int off = 32; off; off >>= 1) acc += __shfl_down(acc, off);
    float mf = (float)(acc * 0.04 / (double)SEG);
    *mf_out = mf;
    // m - start - (128 - start) == m - 128 (Sterbenz-exact)
    *ai_out = (int)rintf(mf - 128.0f);
}

__device__ inline float cv_from_sums(const unsigned long long* __restrict__ cvsums,
                                     int b, int axis) {
    double ts  = 960000.0;                 // Sum(n) = NS*SEG exactly
    double ts2 = (double)cvsums[b * 2 + axis];   // exact integer
    const double N = (double)(NS * ND);
    double mean = ts / N;
    double var  = (ts2 - ts * ts / N) / (N - 1.0);
    return (float)(mean + 3.0 * sqrt(var));
}

// ---------------- Kernel 1: histograms + compact + zero + exact cv sums ----
// Coalesced: lane-consecutive float4 loads at 4 big strides; compact's
// internal event order is permuted, which is semantically free (all consumers
// are order-independent: atomicOr / atomicAdd / popcount).
__global__ __launch_bounds__(256) void hist_kernel(const float* __restrict__ events,
                                                   float* __restrict__ alongX,
                                                   float* __restrict__ alongY,
                                                   unsigned* __restrict__ compact,
                                                   unsigned* __restrict__ container,
                                                   unsigned* __restrict__ masks,
                                                   unsigned long long* __restrict__ cvsums) {
    __shared__ unsigned hx[4][ND], hy[4][ND];   // 8 KB
    __shared__ unsigned long long qredX[4], qredY[4];
    int tid = threadIdx.x;
    int blk = blockIdx.x;
    int b = blk / NS, c = blk % NS;
    int wave = tid >> 6, lane = tid & 63;
    #pragma unroll
    for (int j = 0; j < 4; j++) { hx[j][tid] = 0; hy[j][tid] = 0; }
    // zero-fold: container (4 MB) + masks (1.1 MB) + accumulators
    {
        uint4 z = {0u, 0u, 0u, 0u};
        for (int i = blk * 256 + tid; i < 262144; i += NB * NS * 256)
            ((uint4*)container)[i] = z;
        for (int i = blk * 256 + tid; i < 71680; i += NB * NS * 256)
            ((uint4*)masks)[i] = z;
        if (blk == 0 && tid < NB * 2) cvsums[tid] = 0ull;
    }
    __syncthreads();
    size_t base = (size_t)b * NEV + (size_t)c * SEG;
    const float4* ev4 = (const float4*)(events + base * 2);   // 2 events per float4
    bool wr = (c >= S_IDX && c < E_IDX);
    uint4* dst = wr ? (uint4*)(compact + ((size_t)b * NCH + (c - S_IDX)) * (SEG / 2)) : nullptr;
    unsigned* HX = hx[wave];
    unsigned* HY = hy[wave];
    for (int k = tid; k < SEG / 8; k += 256) {   // 2500 uint4 outputs / chunk
        // lane-consecutive loads (perfectly coalesced), 4 strided quarters
        float4 v0 = ev4[k], v1 = ev4[2500 + k], v2 = ev4[5000 + k], v3 = ev4[7500 + k];
        int x0 = (int)v0.x, y0 = (int)v0.y, x1 = (int)v0.z, y1 = (int)v0.w;
        int x2 = (int)v1.x, y2 = (int)v1.y, x3 = (int)v1.z, y3 = (int)v1.w;
        int x4 = (int)v2.x, y4 = (int)v2.y, x5 = (int)v2.z, y5 = (int)v2.w;
        int x6 = (int)v3.x, y6 = (int)v3.y, x7 = (int)v3.z, y7 = (int)v3.w;
        x0 = x0 > 255 ? 255 : x0; y0 = y0 > 255 ? 255 : y0;
        x1 = x1 > 255 ? 255 : x1; y1 = y1 > 255 ? 255 : y1;
        x2 = x2 > 255 ? 255 : x2; y2 = y2 > 255 ? 255 : y2;
        x3 = x3 > 255 ? 255 : x3; y3 = y3 > 255 ? 255 : y3;
        x4 = x4 > 255 ? 255 : x4; y4 = y4 > 255 ? 255 : y4;
        x5 = x5 > 255 ? 255 : x5; y5 = y5 > 255 ? 255 : y5;
        x6 = x6 > 255 ? 255 : x6; y6 = y6 > 255 ? 255 : y6;
        x7 = x7 > 255 ? 255 : x7; y7 = y7 > 255 ? 255 : y7;
        atomicAdd(&HX[x0], 1u); atomicAdd(&HY[y0], 1u);
        atomicAdd(&HX[x1], 1u); atomicAdd(&HY[y1], 1u);
        atomicAdd(&HX[x2], 1u); atomicAdd(&HY[y2], 1u);
        atomicAdd(&HX[x3], 1u); atomicAdd(&HY[y3], 1u);
        atomicAdd(&HX[x4], 1u); atomicAdd(&HY[y4], 1u);
        atomicAdd(&HX[x5], 1u); atomicAdd(&HY[y5], 1u);
        atomicAdd(&HX[x6], 1u); atomicAdd(&HY[y6], 1u);
        atomicAdd(&HX[x7], 1u); atomicAdd(&HY[y7], 1u);
        if (wr) {
            uint4 p;
            p.x = (unsigned)(x0 | (y0 << 8)) | ((unsigned)(x1 | (y1 << 8)) << 16);
            p.y = (unsigned)(x2 | (y2 << 8)) | ((unsigned)(x3 | (y3 << 8)) << 16);
            p.z = (unsigned)(x4 | (y4 << 8)) | ((unsigned)(x5 | (y5 << 8)) << 16);
            p.w = (unsigned)(x6 | (y6 << 8)) | ((unsigned)(x7 | (y7 << 8)) << 16);
            dst[k] = p;     // coalesced store, unique slot
        }
    }
    __syncthreads();
    unsigned sx = hx[0][tid] + hx[1][tid] + hx[2][tid] + hx[3][tid];
    unsigned sy = hy[0][tid] + hy[1][tid] + hy[2][tid] + hy[3][tid];
    int o = (b * NS + c) * ND + tid;
    alongX[o] = (float)sx;
    alongY[o] = (float)sy;
    // exact Sum(n^2) per (b,axis): u64, order-independent
    unsigned long long qx = (unsigned long long)sx * sx;
    unsigned long long qy = (unsigned long long)sy * sy;
    for (int off = 32; off; off >>= 1) { qx += __shfl_down(qx, off); qy += __shfl_down(qy, off); }
    if (lane == 0) { qredX[wave] = qx; qredY[wave] = qy; }
    __syncthreads();
    if (tid == 0) {
        atomicAdd(&cvsums[b * 2],     qredX[0] + qredX[1] + qredX[2] + qredX[3]);
        atomicAdd(&cvsums[b * 2 + 1], qredY[0] + qredY[1] + qredY[2] + qredY[3]);
    }
}

// ---------------- Kernel 2: half-res visit masks (self-aligned) ------------
__global__ __launch_bounds__(256) void mask_kernel(const unsigned* __restrict__ compact,
                                                   const float* __restrict__ alongX,
                                                   const float* __restrict__ alongY,
                                                   const unsigned long long* __restrict__ cvsums,
                                                   unsigned* __restrict__ masks) {
    __shared__ unsigned sm[512];
    __shared__ int sal[2];
    int tid = threadIdx.x, blk = blockIdx.x;
    int hi = blk & 1;
    int tile = blk >> 1;
    int b = tile / NCH, ci = tile % NCH, si = S_IDX + ci;
    int wave = tid >> 6, lane = tid & 63;
    sm[tid] = 0; sm[tid + 256] = 0;
    if (wave < 2) {
        const float* along = (wave ? alongY : alongX) + (size_t)b * NS * ND;
        float cv = cv_from_sums(cvsums, b, wave);
        float mf; int ai;
        centroid_pl(along, cv, si, lane, &mf, &ai);
        if (lane == 0) sal[wave] = ai;
    }
    __syncthreads();
    int aX = sal[0], aY = sal[1];
    const uint4* cp = (const uint4*)(compact + ((size_t)b * NCH + ci) * (SEG / 2));
    for (int i = hi * 1250 + tid; i < (hi + 1) * 1250; i += 256) {   // 2500 uint4 total
        uint4 w = cp[i];
        unsigned wsv[4] = {w.x, w.y, w.z, w.w};
        #pragma unroll
        for (int j = 0; j < 4; j++) {
            unsigned v = wsv[j];
            #pragma unroll
            for (int h = 0; h < 2; h++) {
                unsigned e = (h ? (v >> 16) : v) & 0xFFFFu;
                int xs = (int)(e & 255u) - aX; xs = xs < 0 ? 0 : (xs > 255 ? 255 : xs);
                int ys = (int)(e >> 8)   - aY; ys = ys < 0 ? 0 : (ys > 255 ? 255 : ys);
                int iv = (xs >> 1) | ((ys >> 1) << 7);
                atomicOr(&sm[iv >> 5], 1u << (iv & 31));
            }
        }
    }
    __syncthreads();
    unsigned* mo = masks + (size_t)tile * 512;   // zeroed in hist
    unsigned v0 = sm[tid], v1 = sm[tid + 256];
    if (v0) atomicOr(&mo[tid], v0);
    if (v1) atomicOr(&mo[tid + 256], v1);
}

// ---------------- outlier helpers ------------------------------------------
// median10 via a 10-element odd-even transposition sorting network: 45
// compare-exchanges, fully static indexing -> stays in VGPRs (insertion
// sort's runtime-indexed w[j] forced scratch allocation, rule #20).
__device__ inline void cex10(float& a, float& b) {
    float lo = fminf(a, b), hi = fmaxf(a, b);
    a = lo; b = hi;
}

__device__ inline float median10(const float* v) {
    float w0 = v[0], w1 = v[1], w2 = v[2], w3 = v[3], w4 = v[4];
    float w5 = v[5], w6 = v[6], w7 = v[7], w8 = v[8], w9 = v[9];
    #pragma unroll
    for (int r = 0; r < 5; ++r) {
        cex10(w0, w1); cex10(w2, w3); cex10(w4, w5); cex10(w6, w7); cex10(w8, w9);
        cex10(w1, w2); cex10(w3, w4); cex10(w5, w6); cex10(w7, w8);
    }
    return 0.5f * (w4 + w5);
}

__device__ inline bool outlier_flag(const float* w) {
    float med = median10(w);
    float d[10];
    #pragma unroll
    for (int i = 0; i < 10; i++) d[i] = fabsf(w[i] - med);
    float d0 = d[0];
    float mad = median10(d);
    return (0.6745f * d0 / mad) > 2.0f;
}

__device__ inline unsigned wave_sum_u32(unsigned v) {
    for (int off = 32; off; off >>= 1) v += __shfl_xor(v, off);
    return v;
}

// ---------------- Kernel 3: stats + decision walk (1024 thr / batch) -------
// Phase A: 16 waves compute the 96 blur-centroids (6 serial each). Phase B:
// wave 0 runs the serial walk.
__global__ __launch_bounds__(1024) void decide_kernel(const unsigned* __restrict__ masks,
                                                      const float* __restrict__ alongX,
                                                      const float* __restrict__ alongY,
                                                      const unsigned long long* __restrict__ cvsums,
                                                      int* __restrict__ alignedX,
                                                      int* __restrict__ alignedY,
                                                      unsigned long long* __restrict__ commitmask) {
    __shared__ float mlds[2 * NS];
    int b = blockIdx.x, tid = threadIdx.x;
    int wave = tid >> 6, lane = tid & 63;
    float cv0 = cv_from_sums(cvsums, b, 0);
    float cv1 = cv_from_sums(cvsums, b, 1);
    #pragma unroll
    for (int q = 0; q < 6; ++q) {
        int p = wave + 16 * q;             // 0..95
        int ax = p >= NS;
        int sI = p - NS * ax;
        const float* along = (ax ? alongY : alongX) + (size_t)b * NS * ND;
        float mf; int ai;
        centroid_pl(along, ax ? cv1 : cv0, sI, lane, &mf, &ai);
        if (lane == 0) {
            mlds[ax * NS + sI] = mf;
            (ax ? alignedY : alignedX)[b * NS + sI] = ai;
        }
    }
    __syncthreads();
    if (tid < 64) {
        const unsigned* mb = masks + (size_t)b * NCH * 512;
        uint4 v0 = ((const uint4*)mb)[lane * 2];
        uint4 v1 = ((const uint4*)mb)[lane * 2 + 1];
        const uint4* pp = (const uint4*)(mb + 512);
        uint4 p0 = pp[lane * 2], p1 = pp[lane * 2 + 1];
        bool f = false;
        if (lane < N_ITER) {
            const float* mx = &mlds[0];
            const float* my = &mlds[NS];
            f = outlier_flag(&mx[S_IDX + 1 + lane]) || outlier_flag(&my[S_IDX + 1 + lane]);
        }
        unsigned long long omask = __ballot(f);
        unsigned ver[8] = {v0.x, v0.y, v0.z, v0.w, v1.x, v1.y, v1.z, v1.w};
        unsigned pc = 0;
        #pragma unroll
        for (int j = 0; j < 8; j++) pc += __popc(ver[j]);
        unsigned cnt = wave_sum_u32(pc);
        unsigned long long cm = 1ull;          // chunk S_IDX always committed
        for (int idx = 1; idx < NCH; ++idx) {
            uint4 c0 = p0, c1 = p1;
            if (idx + 1 < NCH) {
                const uint4* np = (const uint4*)(mb + (size_t)(idx + 1) * 512);
                p0 = np[lane * 2]; p1 = np[lane * 2 + 1];
            }
            unsigned del[8] = {c0.x, c0.y, c0.z, c0.w, c1.x, c1.y, c1.z, c1.w};
            unsigned nl = 0;
            #pragma unroll
            for (int j = 0; j < 8; j++) nl += __popc(del[j] & ~ver[j]);
            unsigned ni = wave_sum_u32(nl);
            bool is_o = (omask >> (idx - 1)) & 1;
            if (!is_o) {
                unsigned cn = cnt + ni;
                float ratio = (float)ni / (float)cn;   // exact ints in f32 div — matches jax
                if (ratio < 0.1f) break;
                cm |= 1ull << idx;
                cnt = cn;
                #pragma unroll
                for (int j = 0; j < 8; j++) ver[j] |= del[j];
            }
        }
        if (lane == 0) commitmask[b] = cm;
    }
}

// ---------------- Kernel 4: commit (4 quarter-blocks / chunk) --------------
__global__ __launch_bounds__(256) void commit_kernel(const unsigned* __restrict__ compact,
                                                     const int* __restrict__ alignedX,
                                                     const int* __restrict__ alignedY,
                                                     const unsigned long long* __restrict__ commitmask,
                                                     unsigned* __restrict__ container) {
    int blk = blockIdx.x, tid = threadIdx.x;
    int qi = blk & 3;
    int tile = blk >> 2;
    int b = tile / NCH, ci = tile % NCH;
    if (!((commitmask[b] >> ci) & 1ull)) return;
    int si = S_IDX + ci;
    int aX = alignedX[b * NS + si], aY = alignedY[b * NS + si];
    unsigned* cont = container + (size_t)b * 65536;
    const uint4* cp = (const uint4*)(compact + ((size_t)b * NCH + ci) * (SEG / 2));
    for (int i = qi * 625 + tid; i < (qi + 1) * 625; i += 256) {     // 2500 uint4 total
        uint4 w = cp[i];
        unsigned wsv[4] = {w.x, w.y, w.z, w.w};
        #pragma unroll
        for (int j = 0; j < 4; j++) {
            unsigned v = wsv[j];
            #pragma unroll
            for (int h = 0; h < 2; h++) {
                unsigned e = (h ? (v >> 16) : v) & 0xFFFFu;
                int xs = (int)(e & 255u) - aX; xs = xs < 0 ? 0 : (xs > 255 ? 255 : xs);
                int ys = (int)(e >> 8)   - aY; ys = ys < 0 ? 0 : (ys > 255 ? 255 : ys);
                atomicAdd(&cont[xs | (ys << 8)], 1u);
            }
        }
    }
}

// ---------------- Kernel 5: cv + clip/normalize (one block / batch) --------
// Pass 1: exact u64 sums over this batch's container (order-independent ints
// -> identical doubles -> identical cv vs the split version). Pass 2: the
// container is L2-hot; clip/normalize and write out. (Validated in round 2.)
__global__ __launch_bounds__(1024) void cvfinish_kernel(const unsigned* __restrict__ container,
                                                        float* __restrict__ out) {
    __shared__ unsigned long long sA[16], sB[16];
    __shared__ float cvs;
    int b = blockIdx.x, tid = threadIdx.x;
    const uint4* c4 = (const uint4*)(container + (size_t)b * 65536);
    unsigned long long s = 0, s2 = 0;
    for (int i = tid; i < 16384; i += 1024) {
        uint4 v = c4[i];
        s  += (unsigned long long)v.x + v.y + v.z + v.w;
        s2 += (unsigned long long)v.x * v.x + (unsigned long long)v.y * v.y
            + (unsigned long long)v.z * v.z + (unsigned long long)v.w * v.w;
    }
    for (int off = 32; off; off >>= 1) { s += __shfl_down(s, off); s2 += __shfl_down(s2, off); }
    if ((tid & 63) == 0) { sA[tid >> 6] = s; sB[tid >> 6] = s2; }
    __syncthreads();
    if (tid == 0) {
        unsigned long long S = 0, S2 = 0;
        #pragma unroll
        for (int w = 0; w < 16; w++) { S += sA[w]; S2 += sB[w]; }
        double ts  = (double)S;
        double ts2 = (double)S2;
        double mean = ts / 65536.0;
        double var  = (ts2 - ts * ts / 65536.0) / 65535.0;
        cvs = (float)(mean + 3.0 * sqrt(var));
    }
    __syncthreads();
    float cv = cvs;
    float4* o4 = (float4*)out + (size_t)b * 16384;
    for (int i = tid; i < 16384; i += 1024) {
        uint4 v = c4[i];
        float4 o;
        o.x = fminf((float)v.x, cv) / cv;
        o.y = fminf((float)v.y, cv) / cv;
        o.z = fminf((float)v.z, cv) / cv;
        o.w = fminf((float)v.w, cv) / cv;
        o4[i] = o;
    }
}

// ---------------- Launcher -------------------------------------------------
extern "C" void kernel_launch(void* const* d_in, const int* in_sizes, int n_in,
                              void* d_out, int out_size, void* d_ws, size_t ws_size,
                              hipStream_t stream) {
    const float* events = (const float*)d_in[0];
    float* out = (float*)d_out;
    char* ws = (char*)d_ws;

    // workspace layout (bytes):
    //   alongX  [16*48*256 f32] @ 0        (786432)
    //   alongY  [16*48*256 f32] @ 786432   (786432)
    //   container[16*65536 u32] @ 1572864  (4194304)
    //   alignedX [16*48 i32]    @ 5767168  (3072)
    //   alignedY [16*48 i32]    @ 5770240  (3072)
    //   commitmask [16 u64]     @ 5779456  (128)
    //   cvsums  [16*2 u64]      @ 5779840  (256)
    //   compact [16*35*10000 u32] @ 6291456 (22400000)
    //   masks   [16*35*512 u32] @ 29360128 (1146880)
    float*    alongX    = (float*)(ws);
    float*    alongY    = (float*)(ws + 786432);
    unsigned* container = (unsigned*)(ws + 1572864);
    int*      alignedX  = (int*)(ws + 5767168);
    int*      alignedY  = (int*)(ws + 5770240);
    unsigned long long* commitmask = (unsigned long long*)(ws + 5779456);
    unsigned long long* cvsums     = (unsigned long long*)(ws + 5779840);
    unsigned* compact   = (unsigned*)(ws + 6291456);
    unsigned* masks     = (unsigned*)(ws + 29360128);

    hist_kernel<<<NB * NS, 256, 0, stream>>>(events, alongX, alongY, compact,
                                             container, masks, cvsums);
    mask_kernel<<<NB * NCH * 2, 256, 0, stream>>>(compact, alongX, alongY, cvsums, masks);
    decide_kernel<<<NB, 1024, 0, stream>>>(masks, alongX, alongY, cvsums,
                                           alignedX, alignedY, commitmask);
    commit_kernel<<<NB * NCH * 4, 256, 0, stream>>>(compact, alignedX, alignedY,
                                                    commitmask, container);
    cvfinish_kernel<<<NB, 1024, 0, stream>>>(container, out);
}

// Round 10
// 251.697 us; speedup vs baseline: 1.0305x; 1.0305x over previous
//
#include <hip/hip_runtime.h>

#define NB 16
#define NEV 960000
#define NS 48
#define SEG 20000
#define S_IDX 3
#define E_IDX 38
#define N_ITER 34
#define ND 256
#define NCH 35          // chunks S_IDX .. E_IDX-1

// ---------------- centroid: preload-then-reduce ----------------------------
// Bit-identical math to the original stats_kernel: same tap order, same
// double accumulation, same 64-lane shfl_down reduction. The 20 taps are
// preloaded into registers (independent, fully unrolled -> static indexing)
// so global latency is paid ONCE per centroid, not 20x serially.
__device__ inline void centroid_pl(const float* __restrict__ along,  // [NS*ND]
                                   float cv, int sI, int lane,
                                   float* mf_out, int* ai_out) {
    float vals[4][5];
    #pragma unroll
    for (int k = 0; k < 4; ++k) {
        int d = lane + 64 * k;
        #pragma unroll
        for (int ds = -2; ds <= 2; ++ds) {
            int ss = sI + ds;
            vals[k][ds + 2] = (ss >= 0 && ss < NS) ? along[ss * ND + d] : 0.0f;
        }
    }
    double acc = 0.0;
    #pragma unroll
    for (int k = 0; k < 4; ++k) {
        int d = lane + 64 * k;
        int lo = d - 2 < 0 ? 0 : d - 2;
        int hi = d + 2 > 255 ? 255 : d + 2;
        double Wd = 0.5 * (double)(lo + hi) * (double)(hi - lo + 1);
        double t = 0.0;
        #pragma unroll
        for (int ds = -2; ds <= 2; ++ds) {
            int ss = sI + ds;
            if (ss >= 0 && ss < NS) t += (double)fminf(vals[k][ds + 2], cv);
        }
        acc += t * Wd;
    }
    for (int off = 32; off; off >>= 1) acc += __shfl_down(acc, off);
    float mf = (float)(acc * 0.04 / (double)SEG);
    *mf_out = mf;
    // m - start - (128 - start) == m - 128 (Sterbenz-exact)
    *ai_out = (int)rintf(mf - 128.0f);
}

__device__ inline float cv_from_sums(const unsigned long long* __restrict__ cvsums,
                                     int b, int axis) {
    double ts  = 960000.0;                 // Sum(n) = NS*SEG exactly
    double ts2 = (double)cvsums[b * 2 + axis];   // exact integer
    const double N = (double)(NS * ND);
    double mean = ts / N;
    double var  = (ts2 - ts * ts / N) / (N - 1.0);
    return (float)(mean + 3.0 * sqrt(var));
}

// ---------------- Kernel 1: histograms + compact + zero + exact cv sums ----
// Coalesced: lane-consecutive float4 loads at 4 big strides; compact's
// internal event order is permuted, which is semantically free (all consumers
// are order-independent: atomicOr / atomicAdd / popcount).
__global__ __launch_bounds__(256) void hist_kernel(const float* __restrict__ events,
                                                   float* __restrict__ alongX,
                                                   float* __restrict__ alongY,
                                                   unsigned* __restrict__ compact,
                                                   unsigned* __restrict__ container,
                                                   unsigned long long* __restrict__ cvsums,
                                                   unsigned long long* __restrict__ sums) {
    __shared__ unsigned hx[4][ND], hy[4][ND];   // 8 KB
    __shared__ unsigned long long qredX[4], qredY[4];
    int tid = threadIdx.x;
    int blk = blockIdx.x;
    int b = blk / NS, c = blk % NS;
    int wave = tid >> 6, lane = tid & 63;
    #pragma unroll
    for (int j = 0; j < 4; j++) { hx[j][tid] = 0; hy[j][tid] = 0; }
    // zero-fold: container (4 MB) + accumulators (masks no longer needs
    // zeroing: mask_kernel now writes every word with plain stores)
    {
        uint4 z = {0u, 0u, 0u, 0u};
        for (int i = blk * 256 + tid; i < 262144; i += NB * NS * 256)
            ((uint4*)container)[i] = z;
        if (blk == 0 && tid < NB * 2) cvsums[tid] = 0ull;
        if (blk == 1 && tid < NB * 2) sums[tid] = 0ull;
    }
    __syncthreads();
    size_t base = (size_t)b * NEV + (size_t)c * SEG;
    const float4* ev4 = (const float4*)(events + base * 2);   // 2 events per float4
    bool wr = (c >= S_IDX && c < E_IDX);
    uint4* dst = wr ? (uint4*)(compact + ((size_t)b * NCH + (c - S_IDX)) * (SEG / 2)) : nullptr;
    unsigned* HX = hx[wave];
    unsigned* HY = hy[wave];
    for (int k = tid; k < SEG / 8; k += 256) {   // 2500 uint4 outputs / chunk
        // lane-consecutive loads (perfectly coalesced), 4 strided quarters
        float4 v0 = ev4[k], v1 = ev4[2500 + k], v2 = ev4[5000 + k], v3 = ev4[7500 + k];
        int x0 = (int)v0.x, y0 = (int)v0.y, x1 = (int)v0.z, y1 = (int)v0.w;
        int x2 = (int)v1.x, y2 = (int)v1.y, x3 = (int)v1.z, y3 = (int)v1.w;
        int x4 = (int)v2.x, y4 = (int)v2.y, x5 = (int)v2.z, y5 = (int)v2.w;
        int x6 = (int)v3.x, y6 = (int)v3.y, x7 = (int)v3.z, y7 = (int)v3.w;
        x0 = x0 > 255 ? 255 : x0; y0 = y0 > 255 ? 255 : y0;
        x1 = x1 > 255 ? 255 : x1; y1 = y1 > 255 ? 255 : y1;
        x2 = x2 > 255 ? 255 : x2; y2 = y2 > 255 ? 255 : y2;
        x3 = x3 > 255 ? 255 : x3; y3 = y3 > 255 ? 255 : y3;
        x4 = x4 > 255 ? 255 : x4; y4 = y4 > 255 ? 255 : y4;
        x5 = x5 > 255 ? 255 : x5; y5 = y5 > 255 ? 255 : y5;
        x6 = x6 > 255 ? 255 : x6; y6 = y6 > 255 ? 255 : y6;
        x7 = x7 > 255 ? 255 : x7; y7 = y7 > 255 ? 255 : y7;
        atomicAdd(&HX[x0], 1u); atomicAdd(&HY[y0], 1u);
        atomicAdd(&HX[x1], 1u); atomicAdd(&HY[y1], 1u);
        atomicAdd(&HX[x2], 1u); atomicAdd(&HY[y2], 1u);
        atomicAdd(&HX[x3], 1u); atomicAdd(&HY[y3], 1u);
        atomicAdd(&HX[x4], 1u); atomicAdd(&HY[y4], 1u);
        atomicAdd(&HX[x5], 1u); atomicAdd(&HY[y5], 1u);
        atomicAdd(&HX[x6], 1u); atomicAdd(&HY[y6], 1u);
        atomicAdd(&HX[x7], 1u); atomicAdd(&HY[y7], 1u);
        if (wr) {
            uint4 p;
            p.x = (unsigned)(x0 | (y0 << 8)) | ((unsigned)(x1 | (y1 << 8)) << 16);
            p.y = (unsigned)(x2 | (y2 << 8)) | ((unsigned)(x3 | (y3 << 8)) << 16);
            p.z = (unsigned)(x4 | (y4 << 8)) | ((unsigned)(x5 | (y5 << 8)) << 16);
            p.w = (unsigned)(x6 | (y6 << 8)) | ((unsigned)(x7 | (y7 << 8)) << 16);
            dst[k] = p;     // coalesced store, unique slot
        }
    }
    __syncthreads();
    unsigned sx = hx[0][tid] + hx[1][tid] + hx[2][tid] + hx[3][tid];
    unsigned sy = hy[0][tid] + hy[1][tid] + hy[2][tid] + hy[3][tid];
    int o = (b * NS + c) * ND + tid;
    alongX[o] = (float)sx;
    alongY[o] = (float)sy;
    // exact Sum(n^2) per (b,axis): u64, order-independent
    unsigned long long qx = (unsigned long long)sx * sx;
    unsigned long long qy = (unsigned long long)sy * sy;
    for (int off = 32; off; off >>= 1) { qx += __shfl_down(qx, off); qy += __shfl_down(qy, off); }
    if (lane == 0) { qredX[wave] = qx; qredY[wave] = qy; }
    __syncthreads();
    if (tid == 0) {
        atomicAdd(&cvsums[b * 2],     qredX[0] + qredX[1] + qredX[2] + qredX[3]);
        atomicAdd(&cvsums[b * 2 + 1], qredY[0] + qredY[1] + qredY[2] + qredY[3]);
    }
}

// ---------------- Kernel 2: half-res visit masks (1 block / chunk) ---------
// One block owns a whole chunk: the LDS mask IS the final mask, written with
// plain coalesced stores (no global atomicOr, no pre-zeroed masks buffer),
// and the two alignment centroids are computed once per chunk, not twice.
__global__ __launch_bounds__(256) void mask_kernel(const unsigned* __restrict__ compact,
                                                   const float* __restrict__ alongX,
                                                   const float* __restrict__ alongY,
                                                   const unsigned long long* __restrict__ cvsums,
                                                   unsigned* __restrict__ masks) {
    __shared__ unsigned sm[512];
    __shared__ int sal[2];
    int tid = threadIdx.x, tile = blockIdx.x;
    int b = tile / NCH, ci = tile % NCH, si = S_IDX + ci;
    int wave = tid >> 6, lane = tid & 63;
    sm[tid] = 0; sm[tid + 256] = 0;
    if (wave < 2) {
        const float* along = (wave ? alongY : alongX) + (size_t)b * NS * ND;
        float cv = cv_from_sums(cvsums, b, wave);
        float mf; int ai;
        centroid_pl(along, cv, si, lane, &mf, &ai);
        if (lane == 0) sal[wave] = ai;
    }
    __syncthreads();
    int aX = sal[0], aY = sal[1];
    const uint4* cp = (const uint4*)(compact + ((size_t)b * NCH + ci) * (SEG / 2));
    for (int i = tid; i < SEG / 8; i += 256) {   // 2500 uint4 total
        uint4 w = cp[i];
        unsigned wsv[4] = {w.x, w.y, w.z, w.w};
        #pragma unroll
        for (int j = 0; j < 4; j++) {
            unsigned v = wsv[j];
            #pragma unroll
            for (int h = 0; h < 2; h++) {
                unsigned e = (h ? (v >> 16) : v) & 0xFFFFu;
                int xs = (int)(e & 255u) - aX; xs = xs < 0 ? 0 : (xs > 255 ? 255 : xs);
                int ys = (int)(e >> 8)   - aY; ys = ys < 0 ? 0 : (ys > 255 ? 255 : ys);
                int iv = (xs >> 1) | ((ys >> 1) << 7);
                atomicOr(&sm[iv >> 5], 1u << (iv & 31));
            }
        }
    }
    __syncthreads();
    unsigned* mo = masks + (size_t)tile * 512;
    mo[tid] = sm[tid];
    mo[tid + 256] = sm[tid + 256];
}

// ---------------- outlier helpers ------------------------------------------
// median10 via a 10-element odd-even transposition sorting network: 45
// compare-exchanges, fully static indexing -> stays in VGPRs (insertion
// sort's runtime-indexed w[j] forced scratch allocation, rule #20).
__device__ inline void cex10(float& a, float& b) {
    float lo = fminf(a, b), hi = fmaxf(a, b);
    a = lo; b = hi;
}

__device__ inline float median10(const float* v) {
    float w0 = v[0], w1 = v[1], w2 = v[2], w3 = v[3], w4 = v[4];
    float w5 = v[5], w6 = v[6], w7 = v[7], w8 = v[8], w9 = v[9];
    #pragma unroll
    for (int r = 0; r < 5; ++r) {
        cex10(w0, w1); cex10(w2, w3); cex10(w4, w5); cex10(w6, w7); cex10(w8, w9);
        cex10(w1, w2); cex10(w3, w4); cex10(w5, w6); cex10(w7, w8);
    }
    return 0.5f * (w4 + w5);
}

__device__ inline bool outlier_flag(const float* w) {
    float med = median10(w);
    float d[10];
    #pragma unroll
    for (int i = 0; i < 10; i++) d[i] = fabsf(w[i] - med);
    float d0 = d[0];
    float mad = median10(d);
    return (0.6745f * d0 / mad) > 2.0f;
}

__device__ inline unsigned wave_sum_u32(unsigned v) {
    for (int off = 32; off; off >>= 1) v += __shfl_xor(v, off);
    return v;
}

// ---------------- Kernel 3: stats + decision walk (1024 thr / batch) -------
// Phase A: 16 waves compute the 96 blur-centroids (6 serial each). Phase B:
// wave 0 runs the serial walk.
__global__ __launch_bounds__(1024) void decide_kernel(const unsigned* __restrict__ masks,
                                                      const float* __restrict__ alongX,
                                                      const float* __restrict__ alongY,
                                                      const unsigned long long* __restrict__ cvsums,
                                                      int* __restrict__ alignedX,
                                                      int* __restrict__ alignedY,
                                                      unsigned long long* __restrict__ commitmask) {
    __shared__ float mlds[2 * NS];
    int b = blockIdx.x, tid = threadIdx.x;
    int wave = tid >> 6, lane = tid & 63;
    float cv0 = cv_from_sums(cvsums, b, 0);
    float cv1 = cv_from_sums(cvsums, b, 1);
    #pragma unroll
    for (int q = 0; q < 6; ++q) {
        int p = wave + 16 * q;             // 0..95
        int ax = p >= NS;
        int sI = p - NS * ax;
        const float* along = (ax ? alongY : alongX) + (size_t)b * NS * ND;
        float mf; int ai;
        centroid_pl(along, ax ? cv1 : cv0, sI, lane, &mf, &ai);
        if (lane == 0) {
            mlds[ax * NS + sI] = mf;
            (ax ? alignedY : alignedX)[b * NS + sI] = ai;
        }
    }
    __syncthreads();
    if (tid < 64) {
        const unsigned* mb = masks + (size_t)b * NCH * 512;
        uint4 v0 = ((const uint4*)mb)[lane * 2];
        uint4 v1 = ((const uint4*)mb)[lane * 2 + 1];
        const uint4* pp = (const uint4*)(mb + 512);
        uint4 p0 = pp[lane * 2], p1 = pp[lane * 2 + 1];
        bool f = false;
        if (lane < N_ITER) {
            const float* mx = &mlds[0];
            const float* my = &mlds[NS];
            f = outlier_flag(&mx[S_IDX + 1 + lane]) || outlier_flag(&my[S_IDX + 1 + lane]);
        }
        unsigned long long omask = __ballot(f);
        unsigned ver[8] = {v0.x, v0.y, v0.z, v0.w, v1.x, v1.y, v1.z, v1.w};
        unsigned pc = 0;
        #pragma unroll
        for (int j = 0; j < 8; j++) pc += __popc(ver[j]);
        unsigned cnt = wave_sum_u32(pc);
        unsigned long long cm = 1ull;          // chunk S_IDX always committed
        for (int idx = 1; idx < NCH; ++idx) {
            uint4 c0 = p0, c1 = p1;
            if (idx + 1 < NCH) {
                const uint4* np = (const uint4*)(mb + (size_t)(idx + 1) * 512);
                p0 = np[lane * 2]; p1 = np[lane * 2 + 1];
            }
            unsigned del[8] = {c0.x, c0.y, c0.z, c0.w, c1.x, c1.y, c1.z, c1.w};
            unsigned nl = 0;
            #pragma unroll
            for (int j = 0; j < 8; j++) nl += __popc(del[j] & ~ver[j]);
            unsigned ni = wave_sum_u32(nl);
            bool is_o = (omask >> (idx - 1)) & 1;
            if (!is_o) {
                unsigned cn = cnt + ni;
                float ratio = (float)ni / (float)cn;   // exact ints in f32 div — matches jax
                if (ratio < 0.1f) break;
                cm |= 1ull << idx;
                cnt = cn;
                #pragma unroll
                for (int j = 0; j < 8; j++) ver[j] |= del[j];
            }
        }
        if (lane == 0) commitmask[b] = cm;
    }
}

// ---------------- Kernel 4: commit (4 quarter-blocks / chunk) --------------
__global__ __launch_bounds__(256) void commit_kernel(const unsigned* __restrict__ compact,
                                                     const int* __restrict__ alignedX,
                                                     const int* __restrict__ alignedY,
                                                     const unsigned long long* __restrict__ commitmask,
                                                     unsigned* __restrict__ container) {
    int blk = blockIdx.x, tid = threadIdx.x;
    int qi = blk & 3;
    int tile = blk >> 2;
    int b = tile / NCH, ci = tile % NCH;
    if (!((commitmask[b] >> ci) & 1ull)) return;
    int si = S_IDX + ci;
    int aX = alignedX[b * NS + si], aY = alignedY[b * NS + si];
    unsigned* cont = container + (size_t)b * 65536;
    const uint4* cp = (const uint4*)(compact + ((size_t)b * NCH + ci) * (SEG / 2));
    for (int i = qi * 625 + tid; i < (qi + 1) * 625; i += 256) {     // 2500 uint4 total
        uint4 w = cp[i];
        unsigned wsv[4] = {w.x, w.y, w.z, w.w};
        #pragma unroll
        for (int j = 0; j < 4; j++) {
            unsigned v = wsv[j];
            #pragma unroll
            for (int h = 0; h < 2; h++) {
                unsigned e = (h ? (v >> 16) : v) & 0xFFFFu;
                int xs = (int)(e & 255u) - aX; xs = xs < 0 ? 0 : (xs > 255 ? 255 : xs);
                int ys = (int)(e >> 8)   - aY; ys = ys < 0 ? 0 : (ys > 255 ? 255 : ys);
                atomicAdd(&cont[xs | (ys << 8)], 1u);
            }
        }
    }
}

// ---------------- Kernel 5: per-batch cv partials (exact u64) -------------
__global__ __launch_bounds__(256) void cv_kernel(const unsigned* __restrict__ container,
                                                 unsigned long long* __restrict__ sums) {
    __shared__ unsigned long long sredA[4], sredB[4];
    int tid = threadIdx.x, blk = blockIdx.x;
    int b = blk >> 4, part = blk & 15;
    const uint4* c4 = (const uint4*)(container + (size_t)b * 65536) + part * 1024;
    unsigned long long s = 0, s2 = 0;
    for (int i = tid; i < 1024; i += 256) {
        uint4 v = c4[i];
        s  += (unsigned long long)v.x + v.y + v.z + v.w;
        s2 += (unsigned long long)v.x * v.x + (unsigned long long)v.y * v.y
            + (unsigned long long)v.z * v.z + (unsigned long long)v.w * v.w;
    }
    for (int off = 32; off; off >>= 1) { s += __shfl_down(s, off); s2 += __shfl_down(s2, off); }
    if ((tid & 63) == 0) { sredA[tid >> 6] = s; sredB[tid >> 6] = s2; }
    __syncthreads();
    if (tid == 0) {
        atomicAdd(&sums[b * 2],     sredA[0] + sredA[1] + sredA[2] + sredA[3]);
        atomicAdd(&sums[b * 2 + 1], sredB[0] + sredB[1] + sredB[2] + sredB[3]);
    }
}

// ---------------- Kernel 6: clip/normalize --------------------------------
__global__ __launch_bounds__(256) void finish_kernel(const unsigned* __restrict__ container,
                                                     const unsigned long long* __restrict__ sums,
                                                     float* __restrict__ out) {
    int g = blockIdx.x * 256 + threadIdx.x;        // vec4 index, 262144 total
    int b = g >> 14;                               // 16384 vec4 per batch
    double ts  = (double)sums[b * 2];              // exact: < 2^53
    double ts2 = (double)sums[b * 2 + 1];
    double mean = ts / 65536.0;
    double var  = (ts2 - ts * ts / 65536.0) / 65535.0;
    float cv = (float)(mean + 3.0 * sqrt(var));
    uint4 v = ((const uint4*)container)[g];
    float4 o;
    o.x = fminf((float)v.x, cv) / cv;
    o.y = fminf((float)v.y, cv) / cv;
    o.z = fminf((float)v.z, cv) / cv;
    o.w = fminf((float)v.w, cv) / cv;
    ((float4*)out)[g] = o;
}

// ---------------- Launcher -------------------------------------------------
extern "C" void kernel_launch(void* const* d_in, const int* in_sizes, int n_in,
                              void* d_out, int out_size, void* d_ws, size_t ws_size,
                              hipStream_t stream) {
    const float* events = (const float*)d_in[0];
    float* out = (float*)d_out;
    char* ws = (char*)d_ws;

    // workspace layout (bytes):
    //   alongX  [16*48*256 f32] @ 0        (786432)
    //   alongY  [16*48*256 f32] @ 786432   (786432)
    //   container[16*65536 u32] @ 1572864  (4194304)
    //   alignedX [16*48 i32]    @ 5767168  (3072)
    //   alignedY [16*48 i32]    @ 5770240  (3072)
    //   commitmask [16 u64]     @ 5779456  (128)
    //   sums    [16*2 u64]      @ 5779584  (256)
    //   cvsums  [16*2 u64]      @ 5779840  (256)
    //   compact [16*35*10000 u32] @ 6291456 (22400000)
    //   masks   [16*35*512 u32] @ 29360128 (1146880)
    float*    alongX    = (float*)(ws);
    float*    alongY    = (float*)(ws + 786432);
    unsigned* container = (unsigned*)(ws + 1572864);
    int*      alignedX  = (int*)(ws + 5767168);
    int*      alignedY  = (int*)(ws + 5770240);
    unsigned long long* commitmask = (unsigned long long*)(ws + 5779456);
    unsigned long long* sums       = (unsigned long long*)(ws + 5779584);
    unsigned long long* cvsums     = (unsigned long long*)(ws + 5779840);
    unsigned* compact   = (unsigned*)(ws + 6291456);
    unsigned* masks     = (unsigned*)(ws + 29360128);

    hist_kernel<<<NB * NS, 256, 0, stream>>>(events, alongX, alongY, compact,
                                             container, cvsums, sums);
    mask_kernel<<<NB * NCH, 256, 0, stream>>>(compact, alongX, alongY, cvsums, masks);
    decide_kernel<<<NB, 1024, 0, stream>>>(masks, alongX, alongY, cvsums,
                                           alignedX, alignedY, commitmask);
    commit_kernel<<<NB * NCH * 4, 256, 0, stream>>>(compact, alignedX, alignedY,
                                                    commitmask, container);
    cv_kernel<<<NB * 16, 256, 0, stream>>>(container, sums);
    finish_kernel<<<1024, 256, 0, stream>>>(container, sums, out);
}

// Round 11
// 248.214 us; speedup vs baseline: 1.0450x; 1.0140x over previous
//
#include <hip/hip_runtime.h>

#define NB 16
#define NEV 960000
#define NS 48
#define SEG 20000
#define S_IDX 3
#define E_IDX 38
#define N_ITER 34
#define ND 256
#define NCH 35          // chunks S_IDX .. E_IDX-1

// ---------------- centroid: preload-then-reduce ----------------------------
// Bit-identical math to the original stats_kernel: same tap order, same
// double accumulation, same 64-lane shfl_down reduction. The 20 taps are
// preloaded into registers (independent, fully unrolled -> static indexing)
// so global latency is paid ONCE per centroid, not 20x serially.
__device__ inline void centroid_pl(const float* __restrict__ along,  // [NS*ND]
                                   float cv, int sI, int lane,
                                   float* mf_out, int* ai_out) {
    float vals[4][5];
    #pragma unroll
    for (int k = 0; k < 4; ++k) {
        int d = lane + 64 * k;
        #pragma unroll
        for (int ds = -2; ds <= 2; ++ds) {
            int ss = sI + ds;
            vals[k][ds + 2] = (ss >= 0 && ss < NS) ? along[ss * ND + d] : 0.0f;
        }
    }
    double acc = 0.0;
    #pragma unroll
    for (int k = 0; k < 4; ++k) {
        int d = lane + 64 * k;
        int lo = d - 2 < 0 ? 0 : d - 2;
        int hi = d + 2 > 255 ? 255 : d + 2;
        double Wd = 0.5 * (double)(lo + hi) * (double)(hi - lo + 1);
        double t = 0.0;
        #pragma unroll
        for (int ds = -2; ds <= 2; ++ds) {
            int ss = sI + ds;
            if (ss >= 0 && ss < NS) t += (double)fminf(vals[k][ds + 2], cv);
        }
        acc += t * Wd;
    }
    for (int off = 32; off; off >>= 1) acc += __shfl_down(acc, off);
    float mf = (float)(acc * 0.04 / (double)SEG);
    *mf_out = mf;
    // m - start - (128 - start) == m - 128 (Sterbenz-exact)
    *ai_out = (int)rintf(mf - 128.0f);
}

__device__ inline float cv_from_sums(const unsigned long long* __restrict__ cvsums,
                                     int b, int axis) {
    double ts  = 960000.0;                 // Sum(n) = NS*SEG exactly
    double ts2 = (double)cvsums[b * 2 + axis];   // exact integer
    const double N = (double)(NS * ND);
    double mean = ts / N;
    double var  = (ts2 - ts * ts / N) / (N - 1.0);
    return (float)(mean + 3.0 * sqrt(var));
}

// ---------------- Kernel 1: histograms + compact + zero + exact cv sums ----
// Coalesced: lane-consecutive float4 loads at 4 big strides; compact's
// internal event order is permuted, which is semantically free (all consumers
// are order-independent: atomicOr / atomicAdd / popcount).
__global__ __launch_bounds__(256) void hist_kernel(const float* __restrict__ events,
                                                   float* __restrict__ alongX,
                                                   float* __restrict__ alongY,
                                                   unsigned* __restrict__ compact,
                                                   unsigned* __restrict__ container,
                                                   unsigned long long* __restrict__ cvsums,
                                                   unsigned long long* __restrict__ sums) {
    __shared__ unsigned hx[4][ND], hy[4][ND];   // 8 KB
    __shared__ unsigned long long qredX[4], qredY[4];
    int tid = threadIdx.x;
    int blk = blockIdx.x;
    int b = blk / NS, c = blk % NS;
    int wave = tid >> 6, lane = tid & 63;
    #pragma unroll
    for (int j = 0; j < 4; j++) { hx[j][tid] = 0; hy[j][tid] = 0; }
    // zero-fold: container (4 MB) + accumulators
    {
        uint4 z = {0u, 0u, 0u, 0u};
        for (int i = blk * 256 + tid; i < 262144; i += NB * NS * 256)
            ((uint4*)container)[i] = z;
        if (blk == 0 && tid < NB * 2) cvsums[tid] = 0ull;
        if (blk == 1 && tid < NB * 2) sums[tid] = 0ull;
    }
    __syncthreads();
    size_t base = (size_t)b * NEV + (size_t)c * SEG;
    const float4* ev4 = (const float4*)(events + base * 2);   // 2 events per float4
    bool wr = (c >= S_IDX && c < E_IDX);
    uint4* dst = wr ? (uint4*)(compact + ((size_t)b * NCH + (c - S_IDX)) * (SEG / 2)) : nullptr;
    unsigned* HX = hx[wave];
    unsigned* HY = hy[wave];
    for (int k = tid; k < SEG / 8; k += 256) {   // 2500 uint4 outputs / chunk
        // lane-consecutive loads (perfectly coalesced), 4 strided quarters
        float4 v0 = ev4[k], v1 = ev4[2500 + k], v2 = ev4[5000 + k], v3 = ev4[7500 + k];
        int x0 = (int)v0.x, y0 = (int)v0.y, x1 = (int)v0.z, y1 = (int)v0.w;
        int x2 = (int)v1.x, y2 = (int)v1.y, x3 = (int)v1.z, y3 = (int)v1.w;
        int x4 = (int)v2.x, y4 = (int)v2.y, x5 = (int)v2.z, y5 = (int)v2.w;
        int x6 = (int)v3.x, y6 = (int)v3.y, x7 = (int)v3.z, y7 = (int)v3.w;
        x0 = x0 > 255 ? 255 : x0; y0 = y0 > 255 ? 255 : y0;
        x1 = x1 > 255 ? 255 : x1; y1 = y1 > 255 ? 255 : y1;
        x2 = x2 > 255 ? 255 : x2; y2 = y2 > 255 ? 255 : y2;
        x3 = x3 > 255 ? 255 : x3; y3 = y3 > 255 ? 255 : y3;
        x4 = x4 > 255 ? 255 : x4; y4 = y4 > 255 ? 255 : y4;
        x5 = x5 > 255 ? 255 : x5; y5 = y5 > 255 ? 255 : y5;
        x6 = x6 > 255 ? 255 : x6; y6 = y6 > 255 ? 255 : y6;
        x7 = x7 > 255 ? 255 : x7; y7 = y7 > 255 ? 255 : y7;
        atomicAdd(&HX[x0], 1u); atomicAdd(&HY[y0], 1u);
        atomicAdd(&HX[x1], 1u); atomicAdd(&HY[y1], 1u);
        atomicAdd(&HX[x2], 1u); atomicAdd(&HY[y2], 1u);
        atomicAdd(&HX[x3], 1u); atomicAdd(&HY[y3], 1u);
        atomicAdd(&HX[x4], 1u); atomicAdd(&HY[y4], 1u);
        atomicAdd(&HX[x5], 1u); atomicAdd(&HY[y5], 1u);
        atomicAdd(&HX[x6], 1u); atomicAdd(&HY[y6], 1u);
        atomicAdd(&HX[x7], 1u); atomicAdd(&HY[y7], 1u);
        if (wr) {
            uint4 p;
            p.x = (unsigned)(x0 | (y0 << 8)) | ((unsigned)(x1 | (y1 << 8)) << 16);
            p.y = (unsigned)(x2 | (y2 << 8)) | ((unsigned)(x3 | (y3 << 8)) << 16);
            p.z = (unsigned)(x4 | (y4 << 8)) | ((unsigned)(x5 | (y5 << 8)) << 16);
            p.w = (unsigned)(x6 | (y6 << 8)) | ((unsigned)(x7 | (y7 << 8)) << 16);
            dst[k] = p;     // coalesced store, unique slot
        }
    }
    __syncthreads();
    unsigned sx = hx[0][tid] + hx[1][tid] + hx[2][tid] + hx[3][tid];
    unsigned sy = hy[0][tid] + hy[1][tid] + hy[2][tid] + hy[3][tid];
    int o = (b * NS + c) * ND + tid;
    alongX[o] = (float)sx;
    alongY[o] = (float)sy;
    // exact Sum(n^2) per (b,axis): u64, order-independent
    unsigned long long qx = (unsigned long long)sx * sx;
    unsigned long long qy = (unsigned long long)sy * sy;
    for (int off = 32; off; off >>= 1) { qx += __shfl_down(qx, off); qy += __shfl_down(qy, off); }
    if (lane == 0) { qredX[wave] = qx; qredY[wave] = qy; }
    __syncthreads();
    if (tid == 0) {
        atomicAdd(&cvsums[b * 2],     qredX[0] + qredX[1] + qredX[2] + qredX[3]);
        atomicAdd(&cvsums[b * 2 + 1], qredY[0] + qredY[1] + qredY[2] + qredY[3]);
    }
}

// ---------------- Kernel 2: half-res visit masks (1 block / chunk) ---------
__global__ __launch_bounds__(256) void mask_kernel(const unsigned* __restrict__ compact,
                                                   const float* __restrict__ alongX,
                                                   const float* __restrict__ alongY,
                                                   const unsigned long long* __restrict__ cvsums,
                                                   unsigned* __restrict__ masks) {
    __shared__ unsigned sm[512];
    __shared__ int sal[2];
    int tid = threadIdx.x, tile = blockIdx.x;
    int b = tile / NCH, ci = tile % NCH, si = S_IDX + ci;
    int wave = tid >> 6, lane = tid & 63;
    sm[tid] = 0; sm[tid + 256] = 0;
    if (wave < 2) {
        const float* along = (wave ? alongY : alongX) + (size_t)b * NS * ND;
        float cv = cv_from_sums(cvsums, b, wave);
        float mf; int ai;
        centroid_pl(along, cv, si, lane, &mf, &ai);
        if (lane == 0) sal[wave] = ai;
    }
    __syncthreads();
    int aX = sal[0], aY = sal[1];
    const uint4* cp = (const uint4*)(compact + ((size_t)b * NCH + ci) * (SEG / 2));
    for (int i = tid; i < SEG / 8; i += 256) {   // 2500 uint4 total
        uint4 w = cp[i];
        unsigned wsv[4] = {w.x, w.y, w.z, w.w};
        #pragma unroll
        for (int j = 0; j < 4; j++) {
            unsigned v = wsv[j];
            #pragma unroll
            for (int h = 0; h < 2; h++) {
                unsigned e = (h ? (v >> 16) : v) & 0xFFFFu;
                int xs = (int)(e & 255u) - aX; xs = xs < 0 ? 0 : (xs > 255 ? 255 : xs);
                int ys = (int)(e >> 8)   - aY; ys = ys < 0 ? 0 : (ys > 255 ? 255 : ys);
                int iv = (xs >> 1) | ((ys >> 1) << 7);
                atomicOr(&sm[iv >> 5], 1u << (iv & 31));
            }
        }
    }
    __syncthreads();
    unsigned* mo = masks + (size_t)tile * 512;
    mo[tid] = sm[tid];
    mo[tid + 256] = sm[tid + 256];
}

// ---------------- outlier helpers ------------------------------------------
// median10 via a 10-element odd-even transposition sorting network: 45
// compare-exchanges, fully static indexing -> stays in VGPRs (insertion
// sort's runtime-indexed w[j] forced scratch allocation, rule #20).
__device__ inline void cex10(float& a, float& b) {
    float lo = fminf(a, b), hi = fmaxf(a, b);
    a = lo; b = hi;
}

__device__ inline float median10(const float* v) {
    float w0 = v[0], w1 = v[1], w2 = v[2], w3 = v[3], w4 = v[4];
    float w5 = v[5], w6 = v[6], w7 = v[7], w8 = v[8], w9 = v[9];
    #pragma unroll
    for (int r = 0; r < 5; ++r) {
        cex10(w0, w1); cex10(w2, w3); cex10(w4, w5); cex10(w6, w7); cex10(w8, w9);
        cex10(w1, w2); cex10(w3, w4); cex10(w5, w6); cex10(w7, w8);
    }
    return 0.5f * (w4 + w5);
}

__device__ inline bool outlier_flag(const float* w) {
    float med = median10(w);
    float d[10];
    #pragma unroll
    for (int i = 0; i < 10; i++) d[i] = fabsf(w[i] - med);
    float d0 = d[0];
    float mad = median10(d);
    return (0.6745f * d0 / mad) > 2.0f;
}

__device__ inline unsigned wave_sum_u32(unsigned v) {
    for (int off = 32; off; off >>= 1) v += __shfl_xor(v, off);
    return v;
}

// ---------------- Kernel 3: stats + decision walk (1024 thr / batch) -------
// Phase A: 16 waves compute the 96 blur-centroids (6 serial each). Phase B:
// wave 0 runs the serial walk.
__global__ __launch_bounds__(1024) void decide_kernel(const unsigned* __restrict__ masks,
                                                      const float* __restrict__ alongX,
                                                      const float* __restrict__ alongY,
                                                      const unsigned long long* __restrict__ cvsums,
                                                      int* __restrict__ alignedX,
                                                      int* __restrict__ alignedY,
                                                      unsigned long long* __restrict__ commitmask) {
    __shared__ float mlds[2 * NS];
    int b = blockIdx.x, tid = threadIdx.x;
    int wave = tid >> 6, lane = tid & 63;
    float cv0 = cv_from_sums(cvsums, b, 0);
    float cv1 = cv_from_sums(cvsums, b, 1);
    #pragma unroll
    for (int q = 0; q < 6; ++q) {
        int p = wave + 16 * q;             // 0..95
        int ax = p >= NS;
        int sI = p - NS * ax;
        const float* along = (ax ? alongY : alongX) + (size_t)b * NS * ND;
        float mf; int ai;
        centroid_pl(along, ax ? cv1 : cv0, sI, lane, &mf, &ai);
        if (lane == 0) {
            mlds[ax * NS + sI] = mf;
            (ax ? alignedY : alignedX)[b * NS + sI] = ai;
        }
    }
    __syncthreads();
    if (tid < 64) {
        const unsigned* mb = masks + (size_t)b * NCH * 512;
        uint4 v0 = ((const uint4*)mb)[lane * 2];
        uint4 v1 = ((const uint4*)mb)[lane * 2 + 1];
        const uint4* pp = (const uint4*)(mb + 512);
        uint4 p0 = pp[lane * 2], p1 = pp[lane * 2 + 1];
        bool f = false;
        if (lane < N_ITER) {
            const float* mx = &mlds[0];
            const float* my = &mlds[NS];
            f = outlier_flag(&mx[S_IDX + 1 + lane]) || outlier_flag(&my[S_IDX + 1 + lane]);
        }
        unsigned long long omask = __ballot(f);
        unsigned ver[8] = {v0.x, v0.y, v0.z, v0.w, v1.x, v1.y, v1.z, v1.w};
        unsigned pc = 0;
        #pragma unroll
        for (int j = 0; j < 8; j++) pc += __popc(ver[j]);
        unsigned cnt = wave_sum_u32(pc);
        unsigned long long cm = 1ull;          // chunk S_IDX always committed
        for (int idx = 1; idx < NCH; ++idx) {
            uint4 c0 = p0, c1 = p1;
            if (idx + 1 < NCH) {
                const uint4* np = (const uint4*)(mb + (size_t)(idx + 1) * 512);
                p0 = np[lane * 2]; p1 = np[lane * 2 + 1];
            }
            unsigned del[8] = {c0.x, c0.y, c0.z, c0.w, c1.x, c1.y, c1.z, c1.w};
            unsigned nl = 0;
            #pragma unroll
            for (int j = 0; j < 8; j++) nl += __popc(del[j] & ~ver[j]);
            unsigned ni = wave_sum_u32(nl);
            bool is_o = (omask >> (idx - 1)) & 1;
            if (!is_o) {
                unsigned cn = cnt + ni;
                float ratio = (float)ni / (float)cn;   // exact ints in f32 div — matches jax
                if (ratio < 0.1f) break;
                cm |= 1ull << idx;
                cnt = cn;
                #pragma unroll
                for (int j = 0; j < 8; j++) ver[j] |= del[j];
            }
        }
        if (lane == 0) commitmask[b] = cm;
    }
}

// ---------------- Kernel 4: commit + fused exact cv sums -------------------
// atomicAdd returns the pre-increment value; for a cell ending at n the
// returned olds are exactly {0..n-1} in any interleaving, so
// Sum(2*old+1) == Sum(n^2) exactly (u64, order-independent). Sum(n) is
// 5000 per active quarter-block. This eliminates the cv pass + boundary.
__global__ __launch_bounds__(256) void commit_kernel(const unsigned* __restrict__ compact,
                                                     const int* __restrict__ alignedX,
                                                     const int* __restrict__ alignedY,
                                                     const unsigned long long* __restrict__ commitmask,
                                                     unsigned* __restrict__ container,
                                                     unsigned long long* __restrict__ sums) {
    __shared__ unsigned long long sred[4];
    int blk = blockIdx.x, tid = threadIdx.x;
    int qi = blk & 3;
    int tile = blk >> 2;
    int b = tile / NCH, ci = tile % NCH;
    if (!((commitmask[b] >> ci) & 1ull)) return;
    int si = S_IDX + ci;
    int aX = alignedX[b * NS + si], aY = alignedY[b * NS + si];
    unsigned* cont = container + (size_t)b * 65536;
    const uint4* cp = (const uint4*)(compact + ((size_t)b * NCH + ci) * (SEG / 2));
    unsigned long long s2 = 0;
    for (int i = qi * 625 + tid; i < (qi + 1) * 625; i += 256) {     // 2500 uint4 total
        uint4 w = cp[i];
        unsigned wsv[4] = {w.x, w.y, w.z, w.w};
        #pragma unroll
        for (int j = 0; j < 4; j++) {
            unsigned v = wsv[j];
            #pragma unroll
            for (int h = 0; h < 2; h++) {
                unsigned e = (h ? (v >> 16) : v) & 0xFFFFu;
                int xs = (int)(e & 255u) - aX; xs = xs < 0 ? 0 : (xs > 255 ? 255 : xs);
                int ys = (int)(e >> 8)   - aY; ys = ys < 0 ? 0 : (ys > 255 ? 255 : ys);
                unsigned old = atomicAdd(&cont[xs | (ys << 8)], 1u);
                s2 += 2ull * old + 1ull;
            }
        }
    }
    int wave = tid >> 6, lane = tid & 63;
    for (int off = 32; off; off >>= 1) s2 += __shfl_down(s2, off);
    if (lane == 0) sred[wave] = s2;
    __syncthreads();
    if (tid == 0) {
        atomicAdd(&sums[b * 2],     5000ull);   // 625 uint4 * 8 events, unconditional
        atomicAdd(&sums[b * 2 + 1], sred[0] + sred[1] + sred[2] + sred[3]);
    }
}

// ---------------- Kernel 5: clip/normalize --------------------------------
__global__ __launch_bounds__(256) void finish_kernel(const unsigned* __restrict__ container,
                                                     const unsigned long long* __restrict__ sums,
                                                     float* __restrict__ out) {
    int g = blockIdx.x * 256 + threadIdx.x;        // vec4 index, 262144 total
    int b = g >> 14;                               // 16384 vec4 per batch
    double ts  = (double)sums[b * 2];              // exact: < 2^53
    double ts2 = (double)sums[b * 2 + 1];
    double mean = ts / 65536.0;
    double var  = (ts2 - ts * ts / 65536.0) / 65535.0;
    float cv = (float)(mean + 3.0 * sqrt(var));
    uint4 v = ((const uint4*)container)[g];
    float4 o;
    o.x = fminf((float)v.x, cv) / cv;
    o.y = fminf((float)v.y, cv) / cv;
    o.z = fminf((float)v.z, cv) / cv;
    o.w = fminf((float)v.w, cv) / cv;
    ((float4*)out)[g] = o;
}

// ---------------- Launcher -------------------------------------------------
extern "C" void kernel_launch(void* const* d_in, const int* in_sizes, int n_in,
                              void* d_out, int out_size, void* d_ws, size_t ws_size,
                              hipStream_t stream) {
    const float* events = (const float*)d_in[0];
    float* out = (float*)d_out;
    char* ws = (char*)d_ws;

    // workspace layout (bytes):
    //   alongX  [16*48*256 f32] @ 0        (786432)
    //   alongY  [16*48*256 f32] @ 786432   (786432)
    //   container[16*65536 u32] @ 1572864  (4194304)
    //   alignedX [16*48 i32]    @ 5767168  (3072)
    //   alignedY [16*48 i32]    @ 5770240  (3072)
    //   commitmask [16 u64]     @ 5779456  (128)
    //   sums    [16*2 u64]      @ 5779584  (256)
    //   cvsums  [16*2 u64]      @ 5779840  (256)
    //   compact [16*35*10000 u32] @ 6291456 (22400000)
    //   masks   [16*35*512 u32] @ 29360128 (1146880)
    float*    alongX    = (float*)(ws);
    float*    alongY    = (float*)(ws + 786432);
    unsigned* container = (unsigned*)(ws + 1572864);
    int*      alignedX  = (int*)(ws + 5767168);
    int*      alignedY  = (int*)(ws + 5770240);
    unsigned long long* commitmask = (unsigned long long*)(ws + 5779456);
    unsigned long long* sums       = (unsigned long long*)(ws + 5779584);
    unsigned long long* cvsums     = (unsigned long long*)(ws + 5779840);
    unsigned* compact   = (unsigned*)(ws + 6291456);
    unsigned* masks     = (unsigned*)(ws + 29360128);

    hist_kernel<<<NB * NS, 256, 0, stream>>>(events, alongX, alongY, compact,
                                             container, cvsums, sums);
    mask_kernel<<<NB * NCH, 256, 0, stream>>>(compact, alongX, alongY, cvsums, masks);
    decide_kernel<<<NB, 1024, 0, stream>>>(masks, alongX, alongY, cvsums,
                                           alignedX, alignedY, commitmask);
    commit_kernel<<<NB * NCH * 4, 256, 0, stream>>>(compact, alignedX, alignedY,
                                                    commitmask, container, sums);
    finish_kernel<<<1024, 256, 0, stream>>>(container, sums, out);
}